// Round 5
// baseline (470.880 us; speedup 1.0000x reference)
//
#include <hip/hip_runtime.h>
#include <cstdint>
#include <cstddef>

// Problem constants (fixed by reference setup)
#define B_   16
#define M_   512
#define HID_ 768
#define NH_  12
#define HD_  64

typedef short s16x8 __attribute__((ext_vector_type(8)));
typedef float f32x4 __attribute__((ext_vector_type(4)));
typedef unsigned short u16x8 __attribute__((ext_vector_type(8)));
typedef unsigned short u16x4 __attribute__((ext_vector_type(4)));

#define C0_ 0.00999999977f   /* sqrtf(1e-4f) */

__device__ __forceinline__ unsigned short f2bf(float f) {
    unsigned int u = __builtin_bit_cast(unsigned int, f);
    u = u + 0x7FFFu + ((u >> 16) & 1u);   // RNE truncate to bf16
    return (unsigned short)(u >> 16);
}

// async global->LDS, 16 B per lane; lds dest = wave-uniform base + lane*16
__device__ __forceinline__ void gld_lds16(const void* g, void* lds) {
    __builtin_amdgcn_global_load_lds(
        (const __attribute__((address_space(1))) unsigned int*)g,
        (__attribute__((address_space(3))) unsigned int*)lds,
        16, 0, 0);
}

// Cs index: row-major [64][128] fp32 with per-row 5-bit XOR swizzle.
// All Cs accesses are scalar, so 4B-granular XOR is legal. Bank spread:
// dot-phase reads (consecutive rows, same col) -> (d^lane)&31 = 2-way (free).
__device__ __forceinline__ int csx(int r, int c) {
    return (r << 7) | (c ^ (r & 31));
}

// ---------------------------------------------------------------------------
// Pre-pass (fused): blocks [0,3072): X fp32 -> bf16 row-major (8 el/thread).
//                   blocks [3072,3648): W -> bf16 transposed Wt[n][k], 32x32.
// ---------------------------------------------------------------------------
__launch_bounds__(256)
__global__ void prep(const float* __restrict__ X, const float* __restrict__ W,
                     unsigned short* __restrict__ Xb, unsigned short* __restrict__ Wt) {
    __shared__ float T[32][33];
    const int blk = blockIdx.x;
    const int t   = threadIdx.x;
    if (blk < 3072) {
        const size_t i = ((size_t)blk * 256 + t) * 8;
        const float4 a = *(const float4*)(X + i);
        const float4 b = *(const float4*)(X + i + 4);
        u16x8 v = { f2bf(a.x), f2bf(a.y), f2bf(a.z), f2bf(a.w),
                    f2bf(b.x), f2bf(b.y), f2bf(b.z), f2bf(b.w) };
        *(u16x8*)(Xb + i) = v;
    } else {
        const int tb = blk - 3072;            // 0..575
        const int n0 = (tb % 24) * 32;
        const int k0 = (tb / 24) * 32;
        #pragma unroll
        for (int p = 0; p < 4; ++p) {
            const int r = p * 8 + (t >> 5);   // k_local
            const int c = t & 31;             // n_local
            T[r][c] = W[(size_t)(k0 + r) * HID_ + n0 + c];
        }
        __syncthreads();
        const int nl = t >> 3;                // 0..31
        const int k4 = (t & 7) * 4;
        u16x4 v = { f2bf(T[k4 + 0][nl]), f2bf(T[k4 + 1][nl]),
                    f2bf(T[k4 + 2][nl]), f2bf(T[k4 + 3][nl]) };
        *(u16x4*)(Wt + (size_t)(n0 + nl) * HID_ + k0 + k4) = v;
    }
}

// ---------------------------------------------------------------------------
// Kernel 1 (fused): Q = X@Wq + bq via bf16 MFMA + neighbor dots + na-half
// output fill, all in one kernel. Tile 64x128, BK=64, 4 waves, grid 768
// (exactly 3 blocks/CU). The na half of `out` (201 MB) is a pure function
// of `prior` except at j=i+-1 (patched later by scanstats), so its NT
// stores are interleaved into the K-loop (6 float4/thread/step, issued
// right after the staging barrier -> they retire under the MFMA phase;
// HBM-write overlaps the matrix pipe, m114 mechanism). fill_out then only
// writes the g half -> ~33 us of serial BW removed from the critical path.
// ---------------------------------------------------------------------------
__launch_bounds__(256)
__global__ void gemm_dots(const unsigned short* __restrict__ Xb,
                          const unsigned short* __restrict__ Wt,
                          const float* __restrict__ bq,
                          const float* __restrict__ prior,
                          float* __restrict__ sdot, float* __restrict__ Qedge,
                          float* __restrict__ out) {
    __shared__ float smem[64 * 128];                       // 32 KB exactly
    __shared__ float partial[128];                         // dot d-split combine
    unsigned short* As = (unsigned short*)smem;            // 8 KB (K-loop only)
    unsigned short* Bs = (unsigned short*)smem + 64 * 64;  // 16 KB (K-loop only)
    float* Cs = smem;                                      // epilogue only

    const int tid  = threadIdx.x;
    const int lane = tid & 63;
    const int wave = tid >> 6;
    const int wr   = (wave >> 1) * 32;
    const int wc   = (wave & 1) * 64;
    const int ln   = lane & 15;
    const int quad = lane >> 4;

    // bijective XCD swizzle: 768 blocks = 8 xcd x (16 row-tiles x 6 col-tiles)
    const int bid = blockIdx.x;
    const int li  = bid >> 3;                 // 0..95
    const int by  = ((bid & 7) << 4) + li / 6;
    const int bx  = li % 6;
    const int r0  = by * 64;
    const int n0  = bx * 128;

    // staging geometry: chunk = 8 rows x 128 B; lane -> row lane>>3,
    // stored slot (lane&7)*16 holds logical byte ((lane&7)^(lane>>3))*16.
    const int srow  = lane >> 3;
    const int selem = ((lane & 7) ^ (lane >> 3)) * 8;
    const int swz   = (ln & 7) << 4;          // read-side XOR (row&7 == ln&7)

    // na-fill geometry: block bid owns flat chunk [bid*65536, +65536) of the
    // na half (768*65536 == B*NH*M*M exactly). 64 float4/thread total.
    const size_t half  = (size_t)B_ * NH_ * M_ * M_;
    const int    fbase = bid * 65536 + tid * 4;

    f32x4 acc[2][4] = {};

    for (int kt = 0; kt < HID_ / 64; ++kt) {
        const int k0 = kt * 64;
        // A: 8 chunks (2/wave), B: 16 chunks (4/wave)
        #pragma unroll
        for (int c = wave * 2; c < wave * 2 + 2; ++c) {
            const unsigned short* ga = Xb + (size_t)(r0 + c * 8 + srow) * HID_ + k0 + selem;
            gld_lds16(ga, (char*)As + c * 1024);
        }
        #pragma unroll
        for (int c = wave * 4; c < wave * 4 + 4; ++c) {
            const unsigned short* gb = Wt + (size_t)(n0 + c * 8 + srow) * HID_ + k0 + selem;
            gld_lds16(gb, (char*)Bs + c * 1024);
        }
        __syncthreads();   // compiler emits s_waitcnt vmcnt(0) before s_barrier

        // ---- na-half fill slice for this K-step: loads/stores issued here
        // retire during the MFMA phase below, before the next barrier drain.
        {
            const int qb = kt * 6;
            #pragma unroll
            for (int qq = 0; qq < 6; ++qq) {
                const int q = qb + qq;
                if (q < 64) {
                    const int f   = fbase + (q << 10);
                    const int bh  = f >> 18;
                    const int bb2 = bh / NH_;
                    const int rem = f & 0x3FFFF;
                    const float4 p4 = *(const float4*)(prior + ((size_t)bb2 << 18) + rem);
                    f32x4 na4 = { fmaf(p4.x, 1.f - C0_, C0_), fmaf(p4.y, 1.f - C0_, C0_),
                                  fmaf(p4.z, 1.f - C0_, C0_), fmaf(p4.w, 1.f - C0_, C0_) };
                    __builtin_nontemporal_store(na4, (f32x4*)(out + half + f));
                }
            }
        }

        #pragma unroll
        for (int kk = 0; kk < 2; ++kk) {
            s16x8 af[2], bf[4];
            #pragma unroll
            for (int r = 0; r < 2; ++r)
                af[r] = *(const s16x8*)((const char*)As + (wr + r * 16 + ln) * 128
                                        + ((kk * 64 + quad * 16) ^ swz));
            #pragma unroll
            for (int c = 0; c < 4; ++c)
                bf[c] = *(const s16x8*)((const char*)Bs + (wc + c * 16 + ln) * 128
                                        + ((kk * 64 + quad * 16) ^ swz));
            #pragma unroll
            for (int r = 0; r < 2; ++r)
                #pragma unroll
                for (int c = 0; c < 4; ++c)
                    acc[r][c] = __builtin_amdgcn_mfma_f32_16x16x32_bf16(af[r], bf[c], acc[r][c], 0, 0, 0);
        }
        __syncthreads();   // also protects As/Bs before Cs overwrite (last iter)
    }

    // ---- epilogue A: acc + bias -> Cs  (C/D layout: col=ln, row=quad*4+e)
    #pragma unroll
    for (int c = 0; c < 4; ++c) {
        const int col = wc + c * 16 + ln;
        const float bias = bq[n0 + col];
        #pragma unroll
        for (int r = 0; r < 2; ++r) {
            const int rowb = wr + r * 16 + quad * 4;
            #pragma unroll
            for (int e = 0; e < 4; ++e)
                Cs[csx(rowb + e, col)] = acc[r][c][e] + bias;
        }
    }
    __syncthreads();

    // ---- epilogue B1: export tile-edge Q rows (0 and 63) for boundary pairs
    {
        const int s   = tid >> 7;             // 0: first row, 1: last row
        const int col = tid & 127;
        const int row = s ? 63 : 0;
        Qedge[(size_t)(by * 2 + s) * HID_ + n0 + col] = Cs[csx(row, col)];
    }

    // ---- epilogue B2: in-tile neighbor dots, d-split across thread halves.
    // thread = (pair p = tid&63, head-half hh = (tid>>6)&1, d-half dh = tid>>7)
    // reads rows p, p+1 at same col -> banks (d^lane)&31 = 2-way, free.
    {
        const int p  = tid & 63;
        const int hh = (tid >> 6) & 1;
        const int dh = tid >> 7;
        float s0 = 0.f, s1 = 0.f;
        if (p < 63) {
            const int base = hh * 64 + dh * 32;
            #pragma unroll
            for (int d = 0; d < 32; d += 2) {
                s0 += Cs[csx(p, base + d)]     * Cs[csx(p + 1, base + d)];
                s1 += Cs[csx(p, base + d + 1)] * Cs[csx(p + 1, base + d + 1)];
            }
        }
        if (dh) partial[(hh << 6) | p] = s0 + s1;
        __syncthreads();
        if (!dh && p < 63) {
            const float tot = s0 + s1 + partial[(hh << 6) | p];
            const int g  = by * 64 + p;       // global row
            const int bb = g >> 9;
            const int ii = g & 511;           // in-batch row, (ii&63)<63 here
            const int h  = bx * 2 + hh;
            sdot[(size_t)(bb * NH_ + h) * M_ + ii] = tot * (1.f / 64.f);
        }
    }
}

// ---------------------------------------------------------------------------
// Kernel 2: per-(b,h) softmax + symmetrize + exclusive log-prefix scan,
// PLUS the na-half tridiagonal patch: na[bh][i][i+1]=nsup, na[bh][i+1][i]=nsub
// (gemm_dots wrote the prior-only placeholder there). 192 blocks x 512 thr.
// Cross-tile boundary pairs (i%64==63, i<511) finish their dot from Qedge.
// ---------------------------------------------------------------------------
__launch_bounds__(512)
__global__ void scanstats(const float* __restrict__ sdot, const float* __restrict__ Qedge,
                          const float* __restrict__ prior, const int* __restrict__ mask,
                          float* __restrict__ Ssum, float* __restrict__ out) {
    const int bh = blockIdx.x;
    const int b  = bh / NH_;
    const int h  = bh - b * NH_;
    const int i  = threadIdx.x;
    const int lane = i & 63;
    const int wid  = i >> 6;

    __shared__ float sh_s[M_];
    __shared__ float sh_pp[M_];
    __shared__ float wsum[8];

    float s = 0.f;
    if (i < M_ - 1) {
        if ((i & 63) == 63) {
            // boundary pair: dot(Qedge[last row of tile gby], Qedge[first row of gby+1])
            const int gby = (b << 3) + (i >> 6);
            const float* qa = Qedge + (size_t)(gby * 2 + 1) * HID_ + h * HD_;
            const float* qb = Qedge + (size_t)(gby + 1) * 2 * HID_ + h * HD_;
            float a0 = 0.f, a1 = 0.f;
            #pragma unroll
            for (int d = 0; d < HD_; d += 8) {
                const float4 xa = *(const float4*)(qa + d);
                const float4 xb = *(const float4*)(qb + d);
                const float4 ya = *(const float4*)(qa + d + 4);
                const float4 yb = *(const float4*)(qb + d + 4);
                a0 += xa.x * xb.x + xa.y * xb.y + xa.z * xb.z + xa.w * xb.w;
                a1 += ya.x * yb.x + ya.y * yb.y + ya.z * yb.z + ya.w * yb.w;
            }
            s = (a0 + a1) * (1.f / 64.f);
        } else {
            s = sdot[bh * M_ + i];
        }
    }
    sh_s[i] = s;
    __syncthreads();

    const bool vp = (i > 0)      && (mask[b * M_ + i - 1] > 0);
    const bool vn = (i < M_ - 1) && (mask[b * M_ + i + 1] > 0);
    const float sp = vp ? sh_s[i - 1] : -1e30f;
    const float sn = vn ? s : -1e30f;
    const float mx = fmaxf(sp, sn);
    const float ep = vp ? __expf(sp - mx) : 0.f;
    const float en = vn ? __expf(sn - mx) : 0.f;
    float den = ep + en;
    den = (den > 0.f) ? den : 1.f;
    const float pp = ep / den;
    const float pn = en / den;
    sh_pp[i] = pp;
    __syncthreads();

    float Lv = 0.f;
    if (i < M_ - 1) {
        const float  sym = sqrtf(pn * sh_pp[i + 1] + 1e-4f);
        const size_t pb  = (size_t)b * (M_ * M_);
        const float  prs = prior[pb + (size_t)i * M_ + (i + 1)];
        const float  prb = prior[pb + (size_t)(i + 1) * M_ + i];
        const float  nsup = prs + (1.f - prs) * sym;
        const float  nsub = prb + (1.f - prb) * sym;
        Lv = logf(nsup + 1e-9f);
        // na-half tridiagonal patch (gemm wrote the prior-only placeholder)
        const size_t half = (size_t)B_ * NH_ * M_ * M_;
        const size_t nab  = half + (size_t)bh * (M_ * M_);
        out[nab + (size_t)i * M_ + (i + 1)] = nsup;
        out[nab + (size_t)(i + 1) * M_ + i] = nsub;
    }

    // inclusive wave-shuffle scan, then cross-wave offset, then make exclusive
    float v = Lv;
    #pragma unroll
    for (int off = 1; off < 64; off <<= 1) {
        float tt = __shfl_up(v, off, 64);
        if (lane >= off) v += tt;
    }
    if (lane == 63) wsum[wid] = v;
    __syncthreads();
    float base = 0.f;
    for (int w = 0; w < wid; ++w) base += wsum[w];
    Ssum[bh * M_ + i] = v + base - Lv;   // exclusive prefix
}

// ---------------------------------------------------------------------------
// Kernel 3: g-half fill only (na half already written by gemm+scanstats).
// Block = one (b, row-pair); loops over all 12 heads. Needs only Ssum
// (L2-resident) + one prior-diag scalar per row. 201 MB of NT stores.
// ---------------------------------------------------------------------------
__launch_bounds__(256)
__global__ void fill_out(const float* __restrict__ prior,
                         const float* __restrict__ Ssum,
                         float* __restrict__ out) {
    const int tid = threadIdx.x;
    const int bi  = blockIdx.x;                 // b*256 + ipair
    const int b   = bi >> 8;
    const int i   = ((bi & 255) << 1) | (tid >> 7);
    const int j0  = (tid & 127) * 4;

    // na[i][i] = prior-mix of prior[b][i][i]  (same formula as off-tridiag)
    const float prd = prior[(size_t)b * (M_ * M_) + (size_t)i * (M_ + 1)];
    const float nad = fmaf(prd, 1.f - C0_, C0_);

    #pragma unroll 2
    for (int h = 0; h < NH_; ++h) {
        const int bh = b * NH_ + h;
        const float4 S4 = *(const float4*)(Ssum + (size_t)bh * M_ + j0);
        const float  Si = Ssum[bh * M_ + i];
        const float sv[4] = {S4.x, S4.y, S4.z, S4.w};

        f32x4 ggv;
        #pragma unroll
        for (int e = 0; e < 4; ++e) {
            const int j = j0 + e;
            const float d = sv[e] - Si;
            float g = __expf((j > i) ? d : -d) + 1e-4f;
            if (j == i) g = nad;                       // diag: neibor_attn[i,i]
            ggv[e] = g;
        }

        const size_t off = ((size_t)(bh * M_ + i)) * M_ + j0;
        __builtin_nontemporal_store(ggv, (f32x4*)(out + off));
    }
}

// ---------------------------------------------------------------------------
extern "C" void kernel_launch(void* const* d_in, const int* in_sizes, int n_in,
                              void* d_out, int out_size, void* d_ws, size_t ws_size,
                              hipStream_t stream) {
    const float* X     = (const float*)d_in[0];   // (B, M, HID)
    const float* prior = (const float*)d_in[1];   // (B, 1, M, M)
    const float* Wq    = (const float*)d_in[2];   // (HID, HID)
    const float* bq    = (const float*)d_in[3];   // (HID,)
    const int*   msk   = (const int*)  d_in[4];   // (B, M)
    float* out = (float*)d_out;

    // workspace layout (~15 MB): Ssum | sdot | Qedge | Xb | Wt
    float* Ssum  = (float*)d_ws;
    float* sdot  = Ssum + (size_t)B_ * NH_ * M_;
    float* Qedge = sdot + (size_t)B_ * NH_ * M_;
    unsigned short* Xb = (unsigned short*)(Qedge + (size_t)128 * 2 * HID_);
    unsigned short* Wt = Xb + (size_t)B_ * M_ * HID_;

    prep<<<3072 + 576, 256, 0, stream>>>(X, Wq, Xb, Wt);

    gemm_dots<<<768, 256, 0, stream>>>(Xb, Wt, bq, prior, sdot, Qedge, out);

    scanstats<<<B_ * NH_, M_, 0, stream>>>(sdot, Qedge, prior, msk, Ssum, out);

    fill_out<<<B_ * (M_ / 2), 256, 0, stream>>>(prior, Ssum, out);
}